// Round 3
// baseline (773.762 us; speedup 1.0000x reference)
//
#include <hip/hip_runtime.h>
#include <hip/hip_bf16.h>

// ---------------------------------------------------------------------------
// Multimodal LSTM (x3) -> concat -> PTP layer1 (8 windows, rank 16) -> PTP layer2
// Round 3: MFMA LSTM recurrence (fragment-packed W, bf16 h), PTP1 reads
// h directly in packed-fragment layout, PTP1 B-stage pitch fix, ptp2 k-split.
// ---------------------------------------------------------------------------

namespace {
constexpr int kB  = 256;
constexpr int kT  = 32;
constexpr int kH  = 256;
constexpr int k4H = 1024;
constexpr int kNW = 8;
constexpr int kR  = 16;
constexpr int kO0 = 128;
constexpr int kO1 = 64;
constexpr int kD1 = 3073;   // 4*768 + 1
constexpr int kD2 = 1025;   // 8*128 + 1
constexpr int kGP = 1036;   // gbuf pitch (f32): 16B-aligned rows, ~2-way banks
}

typedef __attribute__((ext_vector_type(8))) short short8;   // 8 bf16 (4 VGPRs)
typedef __attribute__((ext_vector_type(4))) float f32x4;    // MFMA acc
typedef __attribute__((ext_vector_type(4))) unsigned int u32x4;

__device__ __forceinline__ unsigned int pack2bf(float a, float b) {
    unsigned int ua = __builtin_bit_cast(unsigned int, a);
    unsigned int ub = __builtin_bit_cast(unsigned int, b);
    return (ua >> 16) | (ub & 0xffff0000u);
}
__device__ __forceinline__ float sigm(float x) {
    return 1.f / (1.f + __expf(-x));
}
__device__ __forceinline__ float tanh_fast(float x) {
    float a = fabsf(x);
    float t = 1.f - 2.f / (__expf(2.f * a) + 1.f);
    return copysignf(t, x);
}

// ---------------- W_hh (4H,H) fp32 -> MFMA-B-fragment-linear bf16.
// frag (net,w,s,ct): lane l holds col = w*64+ct*16+(l&15), k = s*32+(l>>4)*8+e.
// uint index: (((net*16+w)*8+s)*4+ct)*256 + l*4  (u32x4 per lane)
__global__ void k_prep_wfrag(const float* __restrict__ wa, const float* __restrict__ wv,
                             const float* __restrict__ wtx, unsigned int* __restrict__ wfrag) {
    int g = blockIdx.x * 256 + threadIdx.x;     // 0 .. 98303
    int l  = g & 63;
    int ct = (g >> 6) & 3;
    int s  = (g >> 8) & 7;
    int w  = (g >> 11) & 15;
    int net = g >> 15;
    const float* W = (net == 0) ? wa : (net == 1) ? wv : wtx;
    const int col = w * 64 + ct * 16 + (l & 15);
    const int k0  = s * 32 + (l >> 4) * 8;
    const float* src = W + (size_t)col * 256 + k0;
    float4 f0 = *(const float4*)src;
    float4 f1 = *(const float4*)(src + 4);
    u32x4 v = { pack2bf(f0.x, f0.y), pack2bf(f0.z, f0.w),
                pack2bf(f1.x, f1.y), pack2bf(f1.z, f1.w) };
    *(u32x4*)&wfrag[(size_t)g * 4] = v;
}

// ---------------- MFMA GEMM (NT) for input projections:
// C[m,n] = sum_k A[m,k]*W[n,k] + b1[n] + b2[n].  M=8192, N=1024, K in {128,256,768}.
__global__ __launch_bounds__(512)
void k_mm_proj(const float* __restrict__ A, const float* __restrict__ W,
               const float* __restrict__ b1, const float* __restrict__ b2,
               float* __restrict__ C, int K) {
    __shared__ __align__(16) unsigned int As[256 * 20];
    __shared__ __align__(16) unsigned int Bs[128 * 20];
    const int tid  = threadIdx.x;
    const int lane = tid & 63;
    const int wid  = tid >> 6;
    const int wm   = wid >> 1, wn = wid & 1;
    const int m0 = blockIdx.x * 256, n0 = blockIdx.y * 128;
    const int nstep = K >> 5;

    const int ar = tid >> 1, akq = (tid & 1) * 16;
    const int br = tid >> 2, bkq = (tid & 3) * 8;
    const float* ap = A + (size_t)(m0 + ar) * K + akq;
    const float* wp = W + (size_t)(n0 + br) * K + bkq;

    float4 aR[4], bR[2];
    auto loadA = [&](int s) {
#pragma unroll
        for (int i = 0; i < 4; ++i) aR[i] = *(const float4*)(ap + s * 32 + i * 4);
    };
    auto loadB = [&](int s) {
#pragma unroll
        for (int i = 0; i < 2; ++i) bR[i] = *(const float4*)(wp + s * 32 + i * 4);
    };

    f32x4 acc[4][4];
#pragma unroll
    for (int i = 0; i < 4; ++i)
#pragma unroll
        for (int j = 0; j < 4; ++j) acc[i][j] = (f32x4){0.f, 0.f, 0.f, 0.f};

    loadA(0); loadB(0);
    for (int s = 0; s < nstep; ++s) {
        __syncthreads();
        {
            u32x4 w0 = { pack2bf(aR[0].x, aR[0].y), pack2bf(aR[0].z, aR[0].w),
                         pack2bf(aR[1].x, aR[1].y), pack2bf(aR[1].z, aR[1].w) };
            u32x4 w1 = { pack2bf(aR[2].x, aR[2].y), pack2bf(aR[2].z, aR[2].w),
                         pack2bf(aR[3].x, aR[3].y), pack2bf(aR[3].z, aR[3].w) };
            *(u32x4*)&As[ar * 20 + (akq >> 1)]     = w0;
            *(u32x4*)&As[ar * 20 + (akq >> 1) + 4] = w1;
            u32x4 v0 = { pack2bf(bR[0].x, bR[0].y), pack2bf(bR[0].z, bR[0].w),
                         pack2bf(bR[1].x, bR[1].y), pack2bf(bR[1].z, bR[1].w) };
            *(u32x4*)&Bs[br * 20 + (bkq >> 1)] = v0;
        }
        __syncthreads();
        if (s + 1 < nstep) { loadA(s + 1); loadB(s + 1); }
        short8 af[4], bf[4];
#pragma unroll
        for (int i = 0; i < 4; ++i)
            af[i] = __builtin_bit_cast(short8,
                *(const u32x4*)&As[(wm * 64 + i * 16 + (lane & 15)) * 20 + (lane >> 4) * 4]);
#pragma unroll
        for (int j = 0; j < 4; ++j)
            bf[j] = __builtin_bit_cast(short8,
                *(const u32x4*)&Bs[(wn * 64 + j * 16 + (lane & 15)) * 20 + (lane >> 4) * 4]);
#pragma unroll
        for (int i = 0; i < 4; ++i)
#pragma unroll
            for (int j = 0; j < 4; ++j)
                acc[i][j] = __builtin_amdgcn_mfma_f32_16x16x32_bf16(af[i], bf[j], acc[i][j], 0, 0, 0);
    }
#pragma unroll
    for (int i = 0; i < 4; ++i) {
#pragma unroll
        for (int j = 0; j < 4; ++j) {
            const int col = n0 + wn * 64 + j * 16 + (lane & 15);
            const float badd = b1[col] + b2[col];
#pragma unroll
            for (int e = 0; e < 4; ++e) {
                const int row = m0 + wm * 64 + i * 16 + (lane >> 4) * 4 + e;
                C[(size_t)row * 1024 + col] = acc[i][j][e] + badd;
            }
        }
    }
}

// ---------------- MFMA LSTM recurrence.
// Block = (net, 16 batch rows); 16 waves; wave w owns gate-cols [64w,64w+64).
// W streamed fragment-linear from L2; h bf16 in swizzled LDS; gates via LDS.
// h also stored to hp[] in PTP1 A-fragment-packed layout:
//   hp slot (n, s, mt=bg, lane, e), kk = (t&3)*768 + coloff + d
__global__ __launch_bounds__(1024)
void k_lstm3(const float* __restrict__ xp_a, const float* __restrict__ xp_v,
             const float* __restrict__ xp_t, const unsigned int* __restrict__ wfrag,
             unsigned short* __restrict__ hp) {
    const int net = blockIdx.y;
    const int bg  = blockIdx.x;            // batch group (16 rows)
    const int tid = threadIdx.x;
    const int l   = tid & 63;
    const int w   = tid >> 6;              // wave = col-block AND activation row
    const float* xp = (net == 0) ? xp_a : (net == 1) ? xp_v : xp_t;
    const int coloff = (net == 0) ? 256 : (net == 1) ? 512 : 0;   // cat=[text,audio,video]

    __shared__ __align__(16) unsigned short hA[4096];   // [row16][k256] bf16, 16B XOR swizzle
    __shared__ __align__(16) float gbuf[16 * kGP];      // preactivations [row][1024]
    for (int i = tid; i < 4096; i += 1024) hA[i] = 0;

    const unsigned int* wb = wfrag + (size_t)((net * 16 + w) * 8) * 4 * 256 + l * 4;
    const int arow = l & 15;
    const unsigned int axor  = (arow & 7) << 4;
    const unsigned int abase = arow * 512;

    float c0 = 0.f, c1 = 0.f, c2 = 0.f, c3 = 0.f;      // cell state: row=w, d=4l..4l+3
    __syncthreads();

    for (int t = 0; t < kT; ++t) {
        // xp prefetch: rows (l>>4)*4+e, cols w*64+ct*16+(l&15)
        float xv[4][4];
        {
            const float* xr = xp + ((size_t)(bg * 16 + (l >> 4) * 4) * 32 + t) * 1024
                            + w * 64 + (l & 15);
#pragma unroll
            for (int e = 0; e < 4; ++e)
#pragma unroll
                for (int ct = 0; ct < 4; ++ct)
                    xv[ct][e] = xr[(size_t)e * 32768 + ct * 16];
        }
        // A fragments (h_prev) from swizzled LDS
        u32x4 af[8];
#pragma unroll
        for (int s = 0; s < 8; ++s) {
            unsigned int byte = abase + (((unsigned int)(s * 64 + (l >> 4) * 16)) ^ axor);
            af[s] = *(const u32x4*)((const char*)hA + byte);
        }
        // B stream + MFMA
        f32x4 acc[4];
#pragma unroll
        for (int ct = 0; ct < 4; ++ct) acc[ct] = (f32x4){0.f, 0.f, 0.f, 0.f};
        u32x4 bw[2][4];
#pragma unroll
        for (int ct = 0; ct < 4; ++ct) bw[0][ct] = *(const u32x4*)(wb + (size_t)ct * 256);
#pragma unroll
        for (int s = 0; s < 8; ++s) {
            if (s < 7) {
#pragma unroll
                for (int ct = 0; ct < 4; ++ct)
                    bw[(s + 1) & 1][ct] = *(const u32x4*)(wb + (size_t)((s + 1) * 4 + ct) * 256);
            }
#pragma unroll
            for (int ct = 0; ct < 4; ++ct)
                acc[ct] = __builtin_amdgcn_mfma_f32_16x16x32_bf16(
                    __builtin_bit_cast(short8, af[s]),
                    __builtin_bit_cast(short8, bw[s & 1][ct]), acc[ct], 0, 0, 0);
        }
        // preacts -> gbuf
#pragma unroll
        for (int ct = 0; ct < 4; ++ct)
#pragma unroll
            for (int e = 0; e < 4; ++e)
                gbuf[((l >> 4) * 4 + e) * kGP + w * 64 + ct * 16 + (l & 15)]
                    = acc[ct][e] + xv[ct][e];
        __syncthreads();
        // activations: row = w, d = 4l..4l+3
        const float* gr = gbuf + w * kGP;
        float4 gi = *(const float4*)(gr + 4 * l);
        float4 gf = *(const float4*)(gr + 256 + 4 * l);
        float4 gg = *(const float4*)(gr + 512 + 4 * l);
        float4 go = *(const float4*)(gr + 768 + 4 * l);
        c0 = sigm(gf.x) * c0 + sigm(gi.x) * tanh_fast(gg.x);
        c1 = sigm(gf.y) * c1 + sigm(gi.y) * tanh_fast(gg.y);
        c2 = sigm(gf.z) * c2 + sigm(gi.z) * tanh_fast(gg.z);
        c3 = sigm(gf.w) * c3 + sigm(gi.w) * tanh_fast(gg.w);
        float h0 = sigm(go.x) * tanh_fast(c0);
        float h1 = sigm(go.y) * tanh_fast(c1);
        float h2 = sigm(go.z) * tanh_fast(c2);
        float h3 = sigm(go.w) * tanh_fast(c3);
        uint2 hpk = make_uint2(pack2bf(h0, h1), pack2bf(h2, h3));
        // hA (next step's A operand), swizzled
        *(uint2*)((char*)hA + (w * 512 + ((8 * l) ^ ((w & 7) << 4)))) = hpk;
        // hp packed global (PTP1 A-fragment layout)
        {
            const int n  = t >> 2;
            const int kk = (t & 3) * 768 + coloff + 4 * l;
            const int s  = kk >> 5;
            const int lslot = w | (((kk >> 3) & 3) << 4);
            const size_t byte = ((((size_t)(n * 96 + s) * 16 + bg) * 64 + lslot) * 8
                                 + (kk & 7)) * 2;
            *(uint2*)((char*)hp + byte) = hpk;
        }
        __syncthreads();
    }
}

// ---------------- PTP1 MFMA GEMM: z1p[ks][n][b][r][o] = sum_{d in ks-half} x*F
// A direct from hp (fragment-packed bf16); B fp32 staged->bf16 LDS (pitch 48).
// Block: (r, ks) x n; M=256, N=128, K=1536; 8 waves, wave = 32 rows x 128 cols.
__global__ __launch_bounds__(512)
void k_ptp1_mfma(const unsigned int* __restrict__ hp, const float* __restrict__ factor,
                 float* __restrict__ z1p) {
    __shared__ __align__(16) unsigned short Bs[128 * 48];
    const int tid  = threadIdx.x;
    const int lane = tid & 63;
    const int wid  = tid >> 6;
    const int r  = blockIdx.x >> 1;
    const int ks = blockIdx.x & 1;
    const int n  = blockIdx.y;

    const int bd = tid >> 4;              // 0..31 (d within step)
    const int bo = (tid & 15) * 8;        // o offset
    const float* fp = factor + ((size_t)(n * kR + r) * kD1 + 1 + ks * 1536 + bd) * kO0 + bo;
    const unsigned int* ha = hp + ((size_t)n * 96 + ks * 48) * 16 * 256 + lane * 4;

    f32x4 acc[2][8];
#pragma unroll
    for (int i = 0; i < 2; ++i)
#pragma unroll
        for (int j = 0; j < 8; ++j) acc[i][j] = (f32x4){0.f, 0.f, 0.f, 0.f};

    float4 br[2][2];
    u32x4 af[2][2];
    auto loadB = [&](int s, int q) {
        br[q][0] = *(const float4*)(fp + (size_t)s * 32 * kO0);
        br[q][1] = *(const float4*)(fp + (size_t)s * 32 * kO0 + 4);
    };
    auto loadA = [&](int s, int q) {
#pragma unroll
        for (int i = 0; i < 2; ++i)
            af[q][i] = *(const u32x4*)(ha + ((size_t)s * 16 + (wid * 2 + i)) * 256);
    };
    loadB(0, 0); loadA(0, 0);
#pragma unroll 2
    for (int s = 0; s < 48; ++s) {
        const int q = s & 1;
        __syncthreads();
        {
            float bv[8] = {br[q][0].x, br[q][0].y, br[q][0].z, br[q][0].w,
                           br[q][1].x, br[q][1].y, br[q][1].z, br[q][1].w};
#pragma unroll
            for (int i = 0; i < 8; ++i)
                Bs[(bo + i) * 48 + bd] =
                    (unsigned short)(__builtin_bit_cast(unsigned int, bv[i]) >> 16);
        }
        __syncthreads();
        if (s + 1 < 48) { loadB(s + 1, q ^ 1); loadA(s + 1, q ^ 1); }
        short8 bf[8];
#pragma unroll
        for (int j = 0; j < 8; ++j)
            bf[j] = __builtin_bit_cast(short8,
                *(const u32x4*)&Bs[(j * 16 + (lane & 15)) * 48 + (lane >> 4) * 8]);
#pragma unroll
        for (int i = 0; i < 2; ++i)
#pragma unroll
            for (int j = 0; j < 8; ++j)
                acc[i][j] = __builtin_amdgcn_mfma_f32_16x16x32_bf16(
                    __builtin_bit_cast(short8, af[q][i]), bf[j], acc[i][j], 0, 0, 0);
    }
    const size_t zb = ((size_t)ks * 8 + n) * 256;
#pragma unroll
    for (int i = 0; i < 2; ++i) {
#pragma unroll
        for (int j = 0; j < 8; ++j) {
            const int col = j * 16 + (lane & 15);
#pragma unroll
            for (int e = 0; e < 4; ++e) {
                const int row = (wid * 2 + i) * 16 + (lane >> 4) * 4 + e;
                z1p[((zb + row) * kR + r) * kO0 + col] = acc[i][j][e];
            }
        }
    }
}

// ---------------- PTP1 epilogue: z = part0+part1 + 0.5*F[n,r,0,o]; p=z^3,
// sign-sqrt, L2-normalize over o, f1[b,n,o] = bias + sum_r w*p_hat
__global__ __launch_bounds__(128)
void k_ptp1_post(const float* __restrict__ z1p, const float* __restrict__ factor,
                 const float* __restrict__ w, const float* __restrict__ bias,
                 float* __restrict__ f1) {
    const int b = blockIdx.x;
    const int n = blockIdx.y;
    const int o = threadIdx.x;
    __shared__ float part[2];
    float sv[kR], nrm[kR];
    const size_t zbase = ((size_t)n * kB + b) * kR * kO0;
    constexpr size_t kHalf = (size_t)8 * 256 * kR * kO0;
#pragma unroll
    for (int r = 0; r < kR; ++r) {
        float v = z1p[zbase + r * kO0 + o] + z1p[kHalf + zbase + r * kO0 + o]
                + 0.5f * factor[(size_t)(n * kR + r) * kD1 * kO0 + o];
        float a = fabsf(v);
        float s = copysignf(a * sqrtf(a), v);
        sv[r] = s;
        float t = s * s;
#pragma unroll
        for (int off = 1; off < 64; off <<= 1) t += __shfl_xor(t, off, 64);
        if ((threadIdx.x & 63) == 0) part[threadIdx.x >> 6] = t;
        __syncthreads();
        nrm[r] = sqrtf(part[0] + part[1]);
        __syncthreads();
    }
    float out = bias[n * kO0 + o];
#pragma unroll
    for (int r = 0; r < kR; ++r) out += w[n * kR + r] * sv[r] / nrm[r];
    f1[((size_t)b * kNW + n) * kO0 + o] = out;
}

// ---------------- PTP2 GEMM (k-split 2): z2p[ks][b][r][o]
__global__ __launch_bounds__(256)
void k_ptp2_gemm(const float* __restrict__ f1flat, const float* __restrict__ factor2,
                 float* __restrict__ z2p) {
    const int b0 = blockIdx.x * 32;
    const int r  = blockIdx.y;
    const int ks = blockIdx.z;
    const int tx = threadIdx.x & 63;
    const int ty = threadIdx.x >> 6;
    __shared__ float xs[32][128];
    float acc[8];
#pragma unroll
    for (int i = 0; i < 8; ++i) acc[i] = 0.f;
    const float* F = factor2 + (size_t)r * kD2 * kO1;
    const int kbeg = ks * 512;
    const int kend = ks ? kD2 : 512;

    for (int k0 = kbeg; k0 < kend; k0 += 128) {
        const int len = min(128, kend - k0);
        {
            const int row = threadIdx.x >> 3;
            const int c0  = (threadIdx.x & 7) * 16;
#pragma unroll
            for (int i = 0; i < 16; ++i) {
                int k = k0 + c0 + i;
                float v = (k == 0) ? 0.5f
                        : (k < kD2 ? f1flat[(size_t)(b0 + row) * 1024 + (k - 1)] : 0.f);
                xs[row][c0 + i] = v;
            }
        }
        __syncthreads();
        for (int dd = 0; dd < len; ++dd) {
            float wv = F[(size_t)(k0 + dd) * kO1 + tx];
#pragma unroll
            for (int i = 0; i < 8; ++i) acc[i] = fmaf(xs[ty * 8 + i][dd], wv, acc[i]);
        }
        __syncthreads();
    }
#pragma unroll
    for (int i = 0; i < 8; ++i) {
        const int b = b0 + ty * 8 + i;
        z2p[(size_t)ks * 262144 + ((size_t)b * kR + r) * kO1 + tx] = acc[i];
    }
}

// ---------------- PTP2 epilogue -> final output (B,64) fp32
__global__ __launch_bounds__(64)
void k_ptp2_post(const float* __restrict__ z2p, const float* __restrict__ w2,
                 const float* __restrict__ b2, float* __restrict__ out) {
    const int b = blockIdx.x;
    const int o = threadIdx.x;
    float sv[kR], nrm[kR];
#pragma unroll
    for (int r = 0; r < kR; ++r) {
        float v = z2p[((size_t)b * kR + r) * kO1 + o]
                + z2p[262144 + ((size_t)b * kR + r) * kO1 + o];
        float a = fabsf(v);
        float s = copysignf(a * sqrtf(a), v);
        sv[r] = s;
        float t = s * s;
#pragma unroll
        for (int off = 1; off < 64; off <<= 1) t += __shfl_xor(t, off, 64);
        nrm[r] = sqrtf(t);
    }
    float acc = b2[o];
#pragma unroll
    for (int r = 0; r < kR; ++r) acc += w2[r] * sv[r] / nrm[r];
    out[(size_t)b * kO1 + o] = acc;
}

// ---------------------------------------------------------------------------
extern "C" void kernel_launch(void* const* d_in, const int* in_sizes, int n_in,
                              void* d_out, int out_size, void* d_ws, size_t ws_size,
                              hipStream_t stream) {
    const float* audio_x  = (const float*)d_in[0];
    const float* video_x  = (const float*)d_in[1];
    const float* text_x   = (const float*)d_in[2];
    const float* aw_ih    = (const float*)d_in[3];
    const float* aw_hh    = (const float*)d_in[4];
    const float* ab_ih    = (const float*)d_in[5];
    const float* ab_hh    = (const float*)d_in[6];
    const float* vw_ih    = (const float*)d_in[7];
    const float* vw_hh    = (const float*)d_in[8];
    const float* vb_ih    = (const float*)d_in[9];
    const float* vb_hh    = (const float*)d_in[10];
    const float* txw_ih   = (const float*)d_in[11];
    const float* txw_hh   = (const float*)d_in[12];
    const float* txb_ih   = (const float*)d_in[13];
    const float* txb_hh   = (const float*)d_in[14];
    const float* l1_factor = (const float*)d_in[15];
    const float* l1_weight = (const float*)d_in[16];
    const float* l1_bias   = (const float*)d_in[17];
    const float* l2_factor = (const float*)d_in[18];
    const float* l2_weight = (const float*)d_in[19];
    const float* l2_bias   = (const float*)d_in[20];

    float* ws = (float*)d_ws;
    // workspace layout (floats); total 28,704,768 floats = 114.8 MB
    float* xp_a = ws;                          //  8,388,608  (B*T, 4H)
    float* xp_v = ws + 8388608;                //  8,388,608
    float* xp_t = ws + 16777216;               //  8,388,608
    unsigned short* hp = (unsigned short*)(ws + 25165824);   // 6,291,456 bf16 (packed h)
    unsigned int* wfrag = (unsigned int*)(ws + 28311552);    //   393,216 u32 (frag W_hh)
    // post-LSTM aliases (xp buffers dead)
    float* z1p = xp_a;                         //  8,388,608  (2 k-split partials)
    float* f1  = xp_v;                         //    262,144  (b,n,o)
    float* z2p = xp_v + 262144;                //    524,288  (2 partials)

    // 1) pack recurrent weights to MFMA fragment layout
    k_prep_wfrag<<<384, 256, 0, stream>>>(aw_hh, vw_hh, txw_hh, wfrag);

    // 2) input projections xp = x @ W_ih^T + b_ih + b_hh  (bf16 MFMA)
    dim3 gp(32, 8);
    k_mm_proj<<<gp, 512, 0, stream>>>(audio_x, aw_ih,  ab_ih,  ab_hh,  xp_a, 128);
    k_mm_proj<<<gp, 512, 0, stream>>>(video_x, vw_ih,  vb_ih,  vb_hh,  xp_v, 256);
    k_mm_proj<<<gp, 512, 0, stream>>>(text_x,  txw_ih, txb_ih, txb_hh, xp_t, 768);

    // 3) MFMA LSTM recurrences -> hp (PTP1 fragment-packed bf16)
    k_lstm3<<<dim3(16, 3), 1024, 0, stream>>>(xp_a, xp_v, xp_t, wfrag, hp);

    // 4) PTP layer 1
    k_ptp1_mfma<<<dim3(32, 8), 512, 0, stream>>>((const unsigned int*)hp, l1_factor, z1p);
    k_ptp1_post<<<dim3(256, 8), 128, 0, stream>>>(z1p, l1_factor, l1_weight, l1_bias, f1);

    // 5) PTP layer 2 -> output
    k_ptp2_gemm<<<dim3(8, 16, 2), 256, 0, stream>>>(f1, l2_factor, z2p);
    k_ptp2_post<<<256, 64, 0, stream>>>(z2p, l2_weight, l2_bias, (float*)d_out);
}